// Round 4
// baseline (72.443 us; speedup 1.0000x reference)
//
#include <hip/hip_runtime.h>

// Slater pairwise energy sum on MI355X — round 4 (compile fix of round 3).
// Bottleneck per rocprof (r2): latency-bound gathers (VALUBusy 15%, HBM 5%).
// Fixes: 4-pair unroll with 8 gathers in flight, A/B table in LDS,
// nontemporal pair-stream loads (native clang vector type for the builtin).

#ifndef SLATER_T
#define SLATER_T 16   // number of atom types (A,B are T x T)
#endif

typedef int  vint4  __attribute__((ext_vector_type(4)));   // native vector for nontemporal builtin

__global__ __launch_bounds__(256)
void repack_kernel(const float* __restrict__ coords,
                   const int* __restrict__ types,
                   float4* __restrict__ packed,
                   float* __restrict__ out, int out_size,
                   int n)
{
    int i = blockIdx.x * blockDim.x + threadIdx.x;
    if (i < out_size) out[i] = 0.0f;               // zero output (harness poisons)
    int stride = gridDim.x * blockDim.x;
    for (; i < n; i += stride) {
        float4 v;
        v.x = coords[3 * i + 0];
        v.y = coords[3 * i + 1];
        v.z = coords[3 * i + 2];
        v.w = __int_as_float(types[i]);
        packed[i] = v;
    }
}

__global__ __launch_bounds__(256)
void zero_kernel(float* __restrict__ out, int out_size)
{
    int i = blockIdx.x * blockDim.x + threadIdx.x;
    if (i < out_size) out[i] = 0.0f;
}

template <bool PACKED>
__global__ __launch_bounds__(256)
void slater_kernel(const int* __restrict__ pairs,
                   const float4* __restrict__ packed,
                   const float* __restrict__ coords,
                   const int* __restrict__ types,
                   const float* __restrict__ A,
                   const float* __restrict__ B,
                   const float* __restrict__ box,
                   const int* __restrict__ cutoffp,
                   float* __restrict__ out,
                   int nP)
{
    // ---- A/B table -> LDS (2 KB); removes an L1 gather per pair ----
    __shared__ float2 tab[SLATER_T * SLATER_T];
    if (threadIdx.x < SLATER_T * SLATER_T)
        tab[threadIdx.x] = make_float2(A[threadIdx.x], B[threadIdx.x]);
    __syncthreads();

    // ---- uniform setup ----
    float b00 = box[0], b01 = box[1], b02 = box[2];
    float b10 = box[3], b11 = box[4], b12 = box[5];
    float b20 = box[6], b21 = box[7], b22 = box[8];

    float C00 =  (b11 * b22 - b12 * b21);
    float C01 = -(b10 * b22 - b12 * b20);
    float C02 =  (b10 * b21 - b11 * b20);
    float C10 = -(b01 * b22 - b02 * b21);
    float C11 =  (b00 * b22 - b02 * b20);
    float C12 = -(b00 * b21 - b01 * b20);
    float C20 =  (b01 * b12 - b02 * b11);
    float C21 = -(b00 * b12 - b02 * b10);
    float C22 =  (b00 * b11 - b01 * b10);
    float det = b00 * C00 + b01 * C01 + b02 * C02;
    float inv_det = 1.0f / det;
    float i00 = C00 * inv_det, i01 = C10 * inv_det, i02 = C20 * inv_det;
    float i10 = C01 * inv_det, i11 = C11 * inv_det, i12 = C21 * inv_det;
    float i20 = C02 * inv_det, i21 = C12 * inv_det, i22 = C22 * inv_det;

    float cut = (float)(*cutoffp);

    float acc = 0.0f;
    int tid    = blockIdx.x * blockDim.x + threadIdx.x;
    int stride = gridDim.x * blockDim.x;

    auto fetch = [&](int idx) -> float4 {
        if (PACKED) {
            return packed[idx];                    // one aligned 16B gather
        } else {
            float4 v;
            v.x = coords[3 * idx + 0];
            v.y = coords[3 * idx + 1];
            v.z = coords[3 * idx + 2];
            v.w = __int_as_float(types[idx]);
            return v;
        }
    };

    // geometry + energy for one pair given both endpoint records
    auto body = [&](float4 ca, float4 cb) {
        int ti = __float_as_int(ca.w);
        int tj = __float_as_int(cb.w);
        float2 ab = tab[ti * SLATER_T + tj];       // LDS

        float dx = cb.x - ca.x, dy = cb.y - ca.y, dz = cb.z - ca.z;

        float s0 = dx * i00 + dy * i10 + dz * i20;
        float s1 = dx * i01 + dy * i11 + dz * i21;
        float s2 = dx * i02 + dy * i12 + dz * i22;
        s0 -= rintf(s0);                           // jnp.round == rintf
        s1 -= rintf(s1);
        s2 -= rintf(s2);
        float d0 = s0 * b00 + s1 * b10 + s2 * b20;
        float d1 = s0 * b01 + s1 * b11 + s2 * b21;
        float d2 = s0 * b02 + s1 * b12 + s2 * b22;

        float r = sqrtf(d0 * d0 + d1 * d1 + d2 * d2);
        float x  = ab.y * r;
        float pf = x * x * (1.0f / 3.0f) + x + 1.0f;
        float e  = ab.x * pf * __expf(-x);
        acc += (r <= cut) ? e : 0.0f;
    };

    const vint4* p4 = (const vint4*)pairs;
    int n4 = nP >> 1;                              // int4-groups (2 pairs each)
    const int step = stride * 2;

    int i0 = tid;
    // main loop: 4 pairs / iteration, 8 gathers issued before any compute
    for (; i0 + stride < n4; i0 += step) {
        vint4 pa = __builtin_nontemporal_load(p4 + i0);
        vint4 pb = __builtin_nontemporal_load(p4 + i0 + stride);
        float4 c0 = fetch(pa.x);
        float4 c1 = fetch(pa.y);
        float4 c2 = fetch(pa.z);
        float4 c3 = fetch(pa.w);
        float4 c4 = fetch(pb.x);
        float4 c5 = fetch(pb.y);
        float4 c6 = fetch(pb.z);
        float4 c7 = fetch(pb.w);
        body(c0, c1);
        body(c2, c3);
        body(c4, c5);
        body(c6, c7);
    }
    if (i0 < n4) {                                 // leftover single int4
        vint4 pa = __builtin_nontemporal_load(p4 + i0);
        float4 c0 = fetch(pa.x);
        float4 c1 = fetch(pa.y);
        float4 c2 = fetch(pa.z);
        float4 c3 = fetch(pa.w);
        body(c0, c1);
        body(c2, c3);
    }
    if (tid == 0 && (nP & 1)) {                    // odd final pair
        int ia = pairs[2 * (nP - 1)], ja = pairs[2 * (nP - 1) + 1];
        body(fetch(ia), fetch(ja));
    }

    // ---- reduction: wave shuffle -> LDS -> one atomic per block ----
    #pragma unroll
    for (int off = 32; off > 0; off >>= 1)
        acc += __shfl_down(acc, off, 64);

    __shared__ float wsum[4];
    int lane = threadIdx.x & 63;
    int wid  = threadIdx.x >> 6;
    if (lane == 0) wsum[wid] = acc;
    __syncthreads();
    if (threadIdx.x == 0) {
        float s = wsum[0] + wsum[1] + wsum[2] + wsum[3];
        atomicAdd(out, s);
    }
}

extern "C" void kernel_launch(void* const* d_in, const int* in_sizes, int n_in,
                              void* d_out, int out_size, void* d_ws, size_t ws_size,
                              hipStream_t stream)
{
    const float* coords = (const float*)d_in[0];
    const int*   pairs  = (const int*)d_in[1];   // int32 on device
    const float* box    = (const float*)d_in[2];
    const float* A      = (const float*)d_in[3];
    const float* B      = (const float*)d_in[4];
    const int*   cutoff = (const int*)d_in[5];
    const int*   types  = (const int*)d_in[6];   // int32 on device

    int n  = in_sizes[0] / 3;   // N atoms
    int nP = in_sizes[1] / 2;   // P pairs

    float* out = (float*)d_out;

    size_t need = (size_t)n * sizeof(float4);

    const int THREADS = 256;
    const int BLOCKS  = 2048;   // 256 CU x 8 blocks; grid-stride covers P

    if (ws_size >= need) {
        float4* packed = (float4*)d_ws;
        int rblocks = (n + THREADS - 1) / THREADS;
        if (rblocks > 2048) rblocks = 2048;
        repack_kernel<<<rblocks, THREADS, 0, stream>>>(coords, types, packed,
                                                       out, out_size, n);
        slater_kernel<true><<<BLOCKS, THREADS, 0, stream>>>(
            pairs, packed, nullptr, nullptr, A, B,
            box, cutoff, out, nP);
    } else {
        zero_kernel<<<(out_size + THREADS - 1) / THREADS, THREADS, 0, stream>>>(out, out_size);
        slater_kernel<false><<<BLOCKS, THREADS, 0, stream>>>(
            pairs, nullptr, coords, types, A, B,
            box, cutoff, out, nP);
    }
}

// Round 5
// 70.055 us; speedup vs baseline: 1.0341x; 1.0341x over previous
//
#include <hip/hip_runtime.h>

// Slater pairwise energy sum on MI355X — round 5.
// r2/r4 post-mortem: ~61 outstanding L2 misses/CU sustained (0.31 lines/cyc at
// ~200cyc latency) regardless of per-batch MLP -> either a ~64-MSHR HW cap or
// a duty-cycle cap (gathers only in flight during issue phase, not during the
// ~400cyc compute phase). This round: 3-stage software pipeline sustaining
// 8 gathers in flight per wave THROUGH the compute phase. Decisive experiment.

#ifndef SLATER_T
#define SLATER_T 16
#endif

typedef int vint4 __attribute__((ext_vector_type(4)));

__global__ __launch_bounds__(256)
void repack_kernel(const float* __restrict__ coords,
                   const int* __restrict__ types,
                   float4* __restrict__ packed,
                   float* __restrict__ out, int out_size,
                   int n)
{
    int i = blockIdx.x * blockDim.x + threadIdx.x;
    if (i < out_size) out[i] = 0.0f;               // zero output (harness poisons)
    int stride = gridDim.x * blockDim.x;
    for (; i < n; i += stride) {
        float4 v;
        v.x = coords[3 * i + 0];
        v.y = coords[3 * i + 1];
        v.z = coords[3 * i + 2];
        v.w = __int_as_float(types[i]);
        packed[i] = v;
    }
}

__global__ __launch_bounds__(256)
void zero_kernel(float* __restrict__ out, int out_size)
{
    int i = blockIdx.x * blockDim.x + threadIdx.x;
    if (i < out_size) out[i] = 0.0f;
}

// ---------------- pipelined main kernel (PACKED path) ----------------
__global__ __launch_bounds__(256)
void slater_pipe(const int* __restrict__ pairs,
                 const float4* __restrict__ packed,
                 const float* __restrict__ A,
                 const float* __restrict__ B,
                 const float* __restrict__ box,
                 const int* __restrict__ cutoffp,
                 float* __restrict__ out,
                 int nP)
{
    __shared__ float2 tab[SLATER_T * SLATER_T];
    if (threadIdx.x < SLATER_T * SLATER_T)
        tab[threadIdx.x] = make_float2(A[threadIdx.x], B[threadIdx.x]);
    __syncthreads();

    // uniform setup (scalar loads -> SGPRs)
    float b00 = box[0], b01 = box[1], b02 = box[2];
    float b10 = box[3], b11 = box[4], b12 = box[5];
    float b20 = box[6], b21 = box[7], b22 = box[8];

    float C00 =  (b11 * b22 - b12 * b21);
    float C01 = -(b10 * b22 - b12 * b20);
    float C02 =  (b10 * b21 - b11 * b20);
    float C10 = -(b01 * b22 - b02 * b21);
    float C11 =  (b00 * b22 - b02 * b20);
    float C12 = -(b00 * b21 - b01 * b20);
    float C20 =  (b01 * b12 - b02 * b11);
    float C21 = -(b00 * b12 - b02 * b10);
    float C22 =  (b00 * b11 - b01 * b10);
    float det = b00 * C00 + b01 * C01 + b02 * C02;
    float inv_det = 1.0f / det;
    float i00 = C00 * inv_det, i01 = C10 * inv_det, i02 = C20 * inv_det;
    float i10 = C01 * inv_det, i11 = C11 * inv_det, i12 = C21 * inv_det;
    float i20 = C02 * inv_det, i21 = C12 * inv_det, i22 = C22 * inv_det;

    float cut = (float)(*cutoffp);

    float acc = 0.0f;
    int tid    = blockIdx.x * blockDim.x + threadIdx.x;
    int stride = gridDim.x * blockDim.x;
    const vint4* p4 = (const vint4*)pairs;
    int n4   = nP >> 1;       // int4 groups (2 pairs each)
    int step = stride * 2;    // 2 groups (4 pairs) per iteration

    auto ld4 = [&](int idx, bool v) -> vint4 {
        return __builtin_nontemporal_load(p4 + (v ? idx : 0));
    };
    auto body = [&](float4 ca, float4 cb, bool val) {
        int ti = __float_as_int(ca.w);
        int tj = __float_as_int(cb.w);
        float2 ab = tab[ti * SLATER_T + tj];
        float dx = cb.x - ca.x, dy = cb.y - ca.y, dz = cb.z - ca.z;
        float s0 = dx * i00 + dy * i10 + dz * i20;
        float s1 = dx * i01 + dy * i11 + dz * i21;
        float s2 = dx * i02 + dy * i12 + dz * i22;
        s0 -= rintf(s0);                       // jnp.round == rintf
        s1 -= rintf(s1);
        s2 -= rintf(s2);
        float d0 = s0 * b00 + s1 * b10 + s2 * b20;
        float d1 = s0 * b01 + s1 * b11 + s2 * b21;
        float d2 = s0 * b02 + s1 * b12 + s2 * b22;
        float r = sqrtf(d0 * d0 + d1 * d1 + d2 * d2);
        float x  = ab.y * r;
        float pf = x * x * (1.0f / 3.0f) + x + 1.0f;
        float e  = ab.x * pf * __expf(-x);
        acc += (val && r <= cut) ? e : 0.0f;
    };

    // ---- 3-stage pipeline: pair-load k+2 | gathers k+1 | compute k ----
    int i0 = tid;              // current iteration base group
    int i1 = tid + step;       // next iteration base group
    bool a0 = i0 < n4,          b0 = (i0 + stride) < n4;
    bool a1 = i1 < n4,          b1 = (i1 + stride) < n4;

    vint4 pA = ld4(i0, a0),          pB = ld4(i0 + stride, b0);
    vint4 qA = ld4(i1, a1),          qB = ld4(i1 + stride, b1);

    float4 c0 = packed[pA.x], c1 = packed[pA.y], c2 = packed[pA.z], c3 = packed[pA.w];
    float4 c4 = packed[pB.x], c5 = packed[pB.y], c6 = packed[pB.z], c7 = packed[pB.w];

    while (a0) {
        int i2 = i1 + step;
        bool a2 = i2 < n4, b2 = (i2 + stride) < n4;
        vint4 rA = ld4(i2, a2);
        vint4 rB = ld4(i2 + stride, b2);

        // issue next-iteration gathers (stay in flight through the compute below)
        float4 m0, m1, m2, m3, m4, m5, m6, m7;
        if (a1) { m0 = packed[qA.x]; m1 = packed[qA.y]; m2 = packed[qA.z]; m3 = packed[qA.w]; }
        else    { m0 = m1 = m2 = m3 = make_float4(0.f, 0.f, 0.f, 0.f); }
        if (b1) { m4 = packed[qB.x]; m5 = packed[qB.y]; m6 = packed[qB.z]; m7 = packed[qB.w]; }
        else    { m4 = m5 = m6 = m7 = make_float4(0.f, 0.f, 0.f, 0.f); }
        __builtin_amdgcn_sched_barrier(0);   // keep gather issue above the compute

        body(c0, c1, a0);
        body(c2, c3, a0);
        body(c4, c5, b0);
        body(c6, c7, b0);

        // rotate pipeline registers
        c0 = m0; c1 = m1; c2 = m2; c3 = m3;
        c4 = m4; c5 = m5; c6 = m6; c7 = m7;
        qA = rA; qB = rB;
        a0 = a1; b0 = b1; a1 = a2; b1 = b2;
        i1 = i2;
    }

    if (tid == 0 && (nP & 1)) {               // odd final pair (nP even here, but safe)
        int ia = pairs[2 * (nP - 1)], ja = pairs[2 * (nP - 1) + 1];
        body(packed[ia], packed[ja], true);
    }

    // ---- reduction: wave shuffle -> LDS -> one atomic per block ----
    #pragma unroll
    for (int off = 32; off > 0; off >>= 1)
        acc += __shfl_down(acc, off, 64);

    __shared__ float wsum[4];
    int lane = threadIdx.x & 63;
    int wid  = threadIdx.x >> 6;
    if (lane == 0) wsum[wid] = acc;
    __syncthreads();
    if (threadIdx.x == 0) {
        float s = wsum[0] + wsum[1] + wsum[2] + wsum[3];
        atomicAdd(out, s);
    }
}

// ---------------- fallback (no workspace): simple loop ----------------
__global__ __launch_bounds__(256)
void slater_simple(const int* __restrict__ pairs,
                   const float* __restrict__ coords,
                   const int* __restrict__ types,
                   const float* __restrict__ A,
                   const float* __restrict__ B,
                   const float* __restrict__ box,
                   const int* __restrict__ cutoffp,
                   float* __restrict__ out,
                   int nP)
{
    __shared__ float2 tab[SLATER_T * SLATER_T];
    if (threadIdx.x < SLATER_T * SLATER_T)
        tab[threadIdx.x] = make_float2(A[threadIdx.x], B[threadIdx.x]);
    __syncthreads();

    float b00 = box[0], b01 = box[1], b02 = box[2];
    float b10 = box[3], b11 = box[4], b12 = box[5];
    float b20 = box[6], b21 = box[7], b22 = box[8];
    float C00 =  (b11 * b22 - b12 * b21);
    float C01 = -(b10 * b22 - b12 * b20);
    float C02 =  (b10 * b21 - b11 * b20);
    float C10 = -(b01 * b22 - b02 * b21);
    float C11 =  (b00 * b22 - b02 * b20);
    float C12 = -(b00 * b21 - b01 * b20);
    float C20 =  (b01 * b12 - b02 * b11);
    float C21 = -(b00 * b12 - b02 * b10);
    float C22 =  (b00 * b11 - b01 * b10);
    float det = b00 * C00 + b01 * C01 + b02 * C02;
    float inv_det = 1.0f / det;
    float i00 = C00 * inv_det, i01 = C10 * inv_det, i02 = C20 * inv_det;
    float i10 = C01 * inv_det, i11 = C11 * inv_det, i12 = C21 * inv_det;
    float i20 = C02 * inv_det, i21 = C12 * inv_det, i22 = C22 * inv_det;
    float cut = (float)(*cutoffp);

    float acc = 0.0f;
    int tid    = blockIdx.x * blockDim.x + threadIdx.x;
    int stride = gridDim.x * blockDim.x;
    for (int p = tid; p < nP; p += stride) {
        int ia = pairs[2 * p], ja = pairs[2 * p + 1];
        float ax = coords[3 * ia], ay = coords[3 * ia + 1], az = coords[3 * ia + 2];
        float bx = coords[3 * ja], by = coords[3 * ja + 1], bz = coords[3 * ja + 2];
        int ti = types[ia], tj = types[ja];
        float2 ab = tab[ti * SLATER_T + tj];
        float dx = bx - ax, dy = by - ay, dz = bz - az;
        float s0 = dx * i00 + dy * i10 + dz * i20;
        float s1 = dx * i01 + dy * i11 + dz * i21;
        float s2 = dx * i02 + dy * i12 + dz * i22;
        s0 -= rintf(s0); s1 -= rintf(s1); s2 -= rintf(s2);
        float d0 = s0 * b00 + s1 * b10 + s2 * b20;
        float d1 = s0 * b01 + s1 * b11 + s2 * b21;
        float d2 = s0 * b02 + s1 * b12 + s2 * b22;
        float r = sqrtf(d0 * d0 + d1 * d1 + d2 * d2);
        float x  = ab.y * r;
        float pf = x * x * (1.0f / 3.0f) + x + 1.0f;
        float e  = ab.x * pf * __expf(-x);
        acc += (r <= cut) ? e : 0.0f;
    }

    #pragma unroll
    for (int off = 32; off > 0; off >>= 1)
        acc += __shfl_down(acc, off, 64);
    __shared__ float wsum[4];
    int lane = threadIdx.x & 63;
    int wid  = threadIdx.x >> 6;
    if (lane == 0) wsum[wid] = acc;
    __syncthreads();
    if (threadIdx.x == 0)
        atomicAdd(out, wsum[0] + wsum[1] + wsum[2] + wsum[3]);
}

extern "C" void kernel_launch(void* const* d_in, const int* in_sizes, int n_in,
                              void* d_out, int out_size, void* d_ws, size_t ws_size,
                              hipStream_t stream)
{
    const float* coords = (const float*)d_in[0];
    const int*   pairs  = (const int*)d_in[1];   // int32 on device
    const float* box    = (const float*)d_in[2];
    const float* A      = (const float*)d_in[3];
    const float* B      = (const float*)d_in[4];
    const int*   cutoff = (const int*)d_in[5];
    const int*   types  = (const int*)d_in[6];   // int32 on device

    int n  = in_sizes[0] / 3;   // N atoms
    int nP = in_sizes[1] / 2;   // P pairs

    float* out = (float*)d_out;

    size_t need = (size_t)n * sizeof(float4);

    const int THREADS = 256;
    const int BLOCKS  = 1536;   // 24 waves/CU target; ~4 pipeline iterations/thread

    if (ws_size >= need) {
        float4* packed = (float4*)d_ws;
        int rblocks = (n + THREADS - 1) / THREADS;
        if (rblocks > 2048) rblocks = 2048;
        repack_kernel<<<rblocks, THREADS, 0, stream>>>(coords, types, packed,
                                                       out, out_size, n);
        slater_pipe<<<BLOCKS, THREADS, 0, stream>>>(pairs, packed, A, B,
                                                    box, cutoff, out, nP);
    } else {
        zero_kernel<<<(out_size + THREADS - 1) / THREADS, THREADS, 0, stream>>>(out, out_size);
        slater_simple<<<2048, THREADS, 0, stream>>>(pairs, coords, types, A, B,
                                                    box, cutoff, out, nP);
    }
}